// Round 26
// baseline (51.474 us; speedup 1.0000x reference)
//
#include <hip/hip_runtime.h>

// AttentionConvFull: grouped 1x1 QKV + 5x5 per-channel local attention, FUSED.
// B=4, H=W=56, C=OC=256, G=8, Cg=32, K=5, pad=2.
//
// R26 = R24 body EXACTLY (best bench 40.2us: MFMA projection, wTs in LDS,
// split kv/q MFMA passes, padded LDS) with ONE change:
// __launch_bounds__(256,1) -> cap 256.
// Why: R23/R24/R25 all clamp VGPR at 128 with WRITE 21-49MB vs 12.5 logical.
// R25 quantified the residual spill at ~6-9 regs/lane (true demand ~135).
// Three targeted diets failed to find the peak; give the allocator room
// instead. Spill round-trip (~9MB HBM + in-loop scratch-load latency)
// disappears; LDS already caps us at 3 blocks/CU so the likely 3-waves/SIMD
// band is ~free. This round is both diagnostic (reveal natural demand) and
// the probable win.
//
// MFMA geometry (m89-verified): D[144x96] = A[144x32] x B[32x96];
// A frag: lane(row=lw&15, k=(lw>>4)*8+j); B frag: B[k][col]=wTs[col][k];
// D: col=lane&15, row=(lane>>4)*4+reg. 16x16x32_f16, 54 MFMA/block.
//
// Register law (R1-R25): cap=256/N; spill signature: VGPR==cap AND
// WRITE >> 12.5MB. Precision: f16 proj + bf16 k,v/rel = 2.34e-2 measured;
// threshold 5.69e-2.

constexpr int TB = 4, TH = 56, TW = 56, TC = 256;
constexpr int G  = 8, CG = 32, PAD = 2;
constexpr int TILE = 8;
constexpr int HT = TILE + 2 * PAD;   // 12
constexpr int NT = TH / TILE;        // 7
constexpr int NPIX_HALO = HT * HT;   // 144
constexpr int XP = 40;               // padded row (halves) for xs16/wTs
constexpr int KP = 33;               // padded row (words) for kvs/qs
constexpr float LOG2E = 1.44269504088896340736f;

typedef __fp16 half2_t __attribute__((ext_vector_type(2)));
typedef __fp16 half8   __attribute__((ext_vector_type(8)));
typedef float  f32x4   __attribute__((ext_vector_type(4)));

__device__ __forceinline__ unsigned h2u(half2_t h) {
    union { half2_t h; unsigned u; } cv; cv.h = h; return cv.u;
}
__device__ __forceinline__ unsigned packbf(float k, float v) {
    return ((__float_as_uint(k) + 0x8000u) >> 16) |
           ((__float_as_uint(v) + 0x8000u) & 0xffff0000u);
}

__global__ __launch_bounds__(256, 1)
void fused_attn_conv_kernel(const float* __restrict__ x,
                            const float* __restrict__ wq,
                            const float* __restrict__ wk,
                            const float* __restrict__ wv,
                            const float* __restrict__ rel,
                            const float* __restrict__ qemb,
                            float* __restrict__ out) {
    __shared__ __align__(16) __fp16 xs16[NPIX_HALO][XP];  // 11.25 KB
    __shared__ __align__(16) __fp16 wTs[3 * CG][XP];      // 7.5 KB
    __shared__ unsigned kvs[NPIX_HALO][KP];               // 18.6 KB
    __shared__ float    qs[TILE * TILE][KP];              // 8.25 KB

    const int bid  = blockIdx.x;
    const int g    = bid & 7;
    const int tile = bid >> 3;
    const int tj   = tile % NT;
    const int ti   = (tile / NT) % NT;
    const int b    = tile / (NT * NT);

    const int t  = threadIdx.x;
    const int c  = t & 31;
    const int p0 = t >> 5;

    const int oc = g * CG + c;           // global out-channel (phase C)
    const int h0 = ti * TILE - PAD, w0 = tj * TILE - PAD;

    // ---- Stage x halo -> xs16 (f16 pairs; 2304 u32, 9/thread, coalesced).
    unsigned (*xsu)[XP / 2] = (unsigned(*)[XP / 2])xs16;
#pragma unroll
    for (int r = 0; r < 9; ++r) {
        const int f  = t + r * 256;          // 0..2303
        const int px = f >> 4, pr = f & 15;  // 16 channel-pairs per pixel
        const int hi = px / HT, hj = px % HT;
        const int gh = h0 + hi, gw = w0 + hj;
        unsigned val = 0u;
        if (gh >= 0 && gh < TH && gw >= 0 && gw < TW) {
            const float2 xv = *(const float2*)(x + (((size_t)b * TH + gh) * TW + gw) * TC
                                                 + g * CG + pr * 2);
            val = h2u(__builtin_amdgcn_cvt_pkrtz(xv.x, xv.y));
        }
        xsu[px][pr] = val;
    }

    // ---- Stage weights -> wTs (rows 0-31 wq, 32-63 wk, 64-95 wv).
    {
        unsigned (*wTu)[XP / 2] = (unsigned(*)[XP / 2])wTs;
        const float* wsrc[3] = {wq, wk, wv};
#pragma unroll
        for (int m = 0; m < 3; ++m) {
#pragma unroll
            for (int r = 0; r < 2; ++r) {
                const int f = t + r * 256;           // 0..511 float2 idx
                const int row = f >> 4, pr = f & 15; // row=oc 0..31
                const float2 wv2 = *(const float2*)(wsrc[m] + ((size_t)(g * CG + row)) * CG
                                                            + pr * 2);
                wTu[m * CG + row][pr] = h2u(__builtin_amdgcn_cvt_pkrtz(wv2.x, wv2.y));
            }
        }
    }

    __syncthreads();   // stage -> MFMA

    const int wvid = t >> 6, lw = t & 63;
    const int lcol = lw & 15;
    const int lko  = (lw >> 4) * 8;
    const f32x4 z4 = {0.f, 0.f, 0.f, 0.f};

    // ---- MFMA kv-pass: 4 B-frags + 4 D live.
    {
        const half8 bk0 = *(const half8*)&wTs[32 + lcol][lko];
        const half8 bk1 = *(const half8*)&wTs[48 + lcol][lko];
        const half8 bv0 = *(const half8*)&wTs[64 + lcol][lko];
        const half8 bv1 = *(const half8*)&wTs[80 + lcol][lko];
#pragma unroll 1
        for (int mt = wvid; mt < 9; mt += 4) {        // waves: 3/2/2/2 M-tiles
            const half8 a = *(const half8*)&xs16[mt * 16 + lcol][lko];
            const f32x4 dk0 = __builtin_amdgcn_mfma_f32_16x16x32_f16(a, bk0, z4, 0, 0, 0);
            const f32x4 dk1 = __builtin_amdgcn_mfma_f32_16x16x32_f16(a, bk1, z4, 0, 0, 0);
            const f32x4 dv0 = __builtin_amdgcn_mfma_f32_16x16x32_f16(a, bv0, z4, 0, 0, 0);
            const f32x4 dv1 = __builtin_amdgcn_mfma_f32_16x16x32_f16(a, bv1, z4, 0, 0, 0);
            const int prow = mt * 16 + ((lw >> 4) << 2);
#pragma unroll
            for (int j = 0; j < 4; ++j) {
                const int px = prow + j;
                kvs[px][lcol]      = packbf(dk0[j], dv0[j]);
                kvs[px][lcol + 16] = packbf(dk1[j], dv1[j]);
            }
        }
    }

    // ---- MFMA q-pass: 2 B-frags + 2 D live.
    {
        const half8 bq0 = *(const half8*)&wTs[ 0 + lcol][lko];
        const half8 bq1 = *(const half8*)&wTs[16 + lcol][lko];
        const float qeL = qemb[g * CG + lcol];
        const float qeH = qemb[g * CG + lcol + 16];
#pragma unroll 1
        for (int mt = wvid; mt < 9; mt += 4) {
            const half8 a = *(const half8*)&xs16[mt * 16 + lcol][lko];
            const f32x4 dq0 = __builtin_amdgcn_mfma_f32_16x16x32_f16(a, bq0, z4, 0, 0, 0);
            const f32x4 dq1 = __builtin_amdgcn_mfma_f32_16x16x32_f16(a, bq1, z4, 0, 0, 0);
            const int prow = mt * 16 + ((lw >> 4) << 2);
#pragma unroll
            for (int j = 0; j < 4; ++j) {
                const int px = prow + j;
                const int hi2 = px / HT, hj2 = px % HT;
                if (hi2 >= PAD && hi2 < PAD + TILE && hj2 >= PAD && hj2 < PAD + TILE) {
                    const int qp = (hi2 - PAD) * TILE + (hj2 - PAD);
                    qs[qp][lcol]      = (dq0[j] + qeL) * LOG2E;
                    qs[qp][lcol + 16] = (dq1[j] + qeH) * LOG2E;
                }
            }
        }
    }

    // rel row -> 13 packed bf16 pairs (even idx = low half, odd = high half)
    unsigned relp[13];
    {
        const float* rp = rel + (size_t)oc * 25;
#pragma unroll
        for (int i = 0; i < 12; ++i) {
            const unsigned lo = __float_as_uint(rp[2 * i])     + 0x8000u;
            const unsigned hi = __float_as_uint(rp[2 * i + 1]) + 0x8000u;
            relp[i] = (lo >> 16) | (hi & 0xffff0000u);
        }
        relp[12] = (__float_as_uint(rp[24]) + 0x8000u) >> 16;
    }

    __syncthreads();   // MFMA -> phase C

    // q (already *log2e) for this thread's 8 column pixels
    float qreg[8];
#pragma unroll
    for (int ii = 0; ii < 8; ++ii) qreg[ii] = qs[ii * TILE + p0][c];

    // ---- Phase C: monolithic row-streaming attention (champion structure).
    float s_[8], a_[8];
#pragma unroll
    for (int ii = 0; ii < 8; ++ii) { s_[ii] = 0.f; a_[ii] = 0.f; }

#pragma unroll
    for (int h = 0; h < HT; ++h) {
        float kr[5], vr[5];
#pragma unroll
        for (int j = 0; j < 5; ++j) {
            const unsigned u = kvs[h * HT + p0 + j][c];
            kr[j] = __uint_as_float(u << 16);          // bf16 k -> f32
            vr[j] = __uint_as_float(u & 0xffff0000u);  // bf16 v -> f32
        }
#pragma unroll
        for (int ii = 0; ii < 8; ++ii) {
            const int di = h - ii;               // compile-time after unroll
            if (di >= 0 && di < 5) {
                const float qv = qreg[ii];
#pragma unroll
                for (int j = 0; j < 5; ++j) {
                    const int idx = di * 5 + j;  // compile-time
                    const unsigned ru = relp[idx >> 1];
                    const float rl = __uint_as_float((idx & 1) ? (ru & 0xffff0000u)
                                                               : (ru << 16));
                    const float e = __builtin_amdgcn_exp2f(qv * (kr[j] + rl));
                    s_[ii] += e;
                    a_[ii] = fmaf(e, vr[j], a_[ii]);
                }
            }
        }
    }

#pragma unroll
    for (int ii = 0; ii < 8; ++ii) {
        const int gh = ti * TILE + ii, gw = tj * TILE + p0;
        out[(((size_t)b * TH + gh) * TW + gw) * TC + g * CG + c] =
            a_[ii] * __builtin_amdgcn_rcpf(s_[ii]);
    }
}

extern "C" void kernel_launch(void* const* d_in, const int* in_sizes, int n_in,
                              void* d_out, int out_size, void* d_ws, size_t ws_size,
                              hipStream_t stream) {
    const float* x    = (const float*)d_in[0];
    const float* wq   = (const float*)d_in[1];
    const float* wk   = (const float*)d_in[2];
    const float* wv   = (const float*)d_in[3];
    const float* rel  = (const float*)d_in[4];
    const float* qemb = (const float*)d_in[5];
    float* out = (float*)d_out;

    const int nblocks = TB * NT * NT * G;   // 4*7*7*8 = 1568
    hipLaunchKernelGGL(fused_attn_conv_kernel, dim3(nblocks), dim3(256), 0, stream,
                       x, wq, wk, wv, rel, qemb, out);
}

// Round 27
// 39.924 us; speedup vs baseline: 1.2893x; 1.2893x over previous
//
#include <hip/hip_runtime.h>

// AttentionConvFull: grouped 1x1 QKV + 5x5 per-channel local attention, FUSED.
// B=4, H=W=56, C=OC=256, G=8, Cg=32, K=5, pad=2.
//
// R27 = R24 body EXACTLY (champion 40.2us) + ONE change: x-staging loop
// #pragma unroll 3 (was full unroll 9).
// Why: R26 measured natural demand = 136 VGPR (cap-256 run, WRITE clean at
// 12.5MB) -> under cap 128 only ~8 regs spill, but R26 also showed paying
// for those 8 regs with the >128 band costs MORE (51.5us vs 40.2). The 9
// fully-unrolled staging loads (~30-40 live regs of loads+addresses) are
// the most plausible peak component; unroll 3 caps in-flight staging at
// ~12 regs. (R25's unroll-3 test was confounded by wTs removal.)
// Decisive signal: VGPR <= 127 AND WRITE == 12.5MB -> spill eliminated
// under the good band. If VGPR==128 still: demand is distributed; R24 is
// the practical plateau.
//
// MFMA geometry (m89-verified): D[144x96] = A[144x32] x B[32x96];
// A frag: lane(row=lw&15, k=(lw>>4)*8+j); B frag: B[k][col]=wTs[col][k];
// D: col=lane&15, row=(lane>>4)*4+reg. 16x16x32_f16, 54 MFMA/block.
//
// Register law (R1-R26): cap=256/N; natural demand 136 (R26); spill
// signature: VGPR==cap AND WRITE >> 12.5MB. Precision: f16 proj + bf16
// k,v/rel = 2.34e-2 measured; threshold 5.69e-2.

constexpr int TB = 4, TH = 56, TW = 56, TC = 256;
constexpr int G  = 8, CG = 32, PAD = 2;
constexpr int TILE = 8;
constexpr int HT = TILE + 2 * PAD;   // 12
constexpr int NT = TH / TILE;        // 7
constexpr int NPIX_HALO = HT * HT;   // 144
constexpr int XP = 40;               // padded row (halves) for xs16/wTs
constexpr int KP = 33;               // padded row (words) for kvs/qs
constexpr float LOG2E = 1.44269504088896340736f;

typedef __fp16 half2_t __attribute__((ext_vector_type(2)));
typedef __fp16 half8   __attribute__((ext_vector_type(8)));
typedef float  f32x4   __attribute__((ext_vector_type(4)));

__device__ __forceinline__ unsigned h2u(half2_t h) {
    union { half2_t h; unsigned u; } cv; cv.h = h; return cv.u;
}
__device__ __forceinline__ unsigned packbf(float k, float v) {
    return ((__float_as_uint(k) + 0x8000u) >> 16) |
           ((__float_as_uint(v) + 0x8000u) & 0xffff0000u);
}

__global__ __launch_bounds__(256, 2)
void fused_attn_conv_kernel(const float* __restrict__ x,
                            const float* __restrict__ wq,
                            const float* __restrict__ wk,
                            const float* __restrict__ wv,
                            const float* __restrict__ rel,
                            const float* __restrict__ qemb,
                            float* __restrict__ out) {
    __shared__ __align__(16) __fp16 xs16[NPIX_HALO][XP];  // 11.25 KB
    __shared__ __align__(16) __fp16 wTs[3 * CG][XP];      // 7.5 KB
    __shared__ unsigned kvs[NPIX_HALO][KP];               // 18.6 KB
    __shared__ float    qs[TILE * TILE][KP];              // 8.25 KB

    const int bid  = blockIdx.x;
    const int g    = bid & 7;
    const int tile = bid >> 3;
    const int tj   = tile % NT;
    const int ti   = (tile / NT) % NT;
    const int b    = tile / (NT * NT);

    const int t  = threadIdx.x;
    const int c  = t & 31;
    const int p0 = t >> 5;

    const int oc = g * CG + c;           // global out-channel (phase C)
    const int h0 = ti * TILE - PAD, w0 = tj * TILE - PAD;

    // ---- Stage x halo -> xs16 (f16 pairs; 2304 u32, 9/thread, coalesced).
    //      unroll 3: cap in-flight staging regs (~12 vs ~36 at full unroll).
    unsigned (*xsu)[XP / 2] = (unsigned(*)[XP / 2])xs16;
#pragma unroll 3
    for (int r = 0; r < 9; ++r) {
        const int f  = t + r * 256;          // 0..2303
        const int px = f >> 4, pr = f & 15;  // 16 channel-pairs per pixel
        const int hi = px / HT, hj = px % HT;
        const int gh = h0 + hi, gw = w0 + hj;
        unsigned val = 0u;
        if (gh >= 0 && gh < TH && gw >= 0 && gw < TW) {
            const float2 xv = *(const float2*)(x + (((size_t)b * TH + gh) * TW + gw) * TC
                                                 + g * CG + pr * 2);
            val = h2u(__builtin_amdgcn_cvt_pkrtz(xv.x, xv.y));
        }
        xsu[px][pr] = val;
    }

    // ---- Stage weights -> wTs (rows 0-31 wq, 32-63 wk, 64-95 wv).
    {
        unsigned (*wTu)[XP / 2] = (unsigned(*)[XP / 2])wTs;
        const float* wsrc[3] = {wq, wk, wv};
#pragma unroll
        for (int m = 0; m < 3; ++m) {
#pragma unroll
            for (int r = 0; r < 2; ++r) {
                const int f = t + r * 256;           // 0..511 float2 idx
                const int row = f >> 4, pr = f & 15; // row=oc 0..31
                const float2 wv2 = *(const float2*)(wsrc[m] + ((size_t)(g * CG + row)) * CG
                                                            + pr * 2);
                wTu[m * CG + row][pr] = h2u(__builtin_amdgcn_cvt_pkrtz(wv2.x, wv2.y));
            }
        }
    }

    __syncthreads();   // stage -> MFMA

    const int wvid = t >> 6, lw = t & 63;
    const int lcol = lw & 15;
    const int lko  = (lw >> 4) * 8;
    const f32x4 z4 = {0.f, 0.f, 0.f, 0.f};

    // ---- MFMA kv-pass: 4 B-frags + 4 D live.
    {
        const half8 bk0 = *(const half8*)&wTs[32 + lcol][lko];
        const half8 bk1 = *(const half8*)&wTs[48 + lcol][lko];
        const half8 bv0 = *(const half8*)&wTs[64 + lcol][lko];
        const half8 bv1 = *(const half8*)&wTs[80 + lcol][lko];
#pragma unroll 1
        for (int mt = wvid; mt < 9; mt += 4) {        // waves: 3/2/2/2 M-tiles
            const half8 a = *(const half8*)&xs16[mt * 16 + lcol][lko];
            const f32x4 dk0 = __builtin_amdgcn_mfma_f32_16x16x32_f16(a, bk0, z4, 0, 0, 0);
            const f32x4 dk1 = __builtin_amdgcn_mfma_f32_16x16x32_f16(a, bk1, z4, 0, 0, 0);
            const f32x4 dv0 = __builtin_amdgcn_mfma_f32_16x16x32_f16(a, bv0, z4, 0, 0, 0);
            const f32x4 dv1 = __builtin_amdgcn_mfma_f32_16x16x32_f16(a, bv1, z4, 0, 0, 0);
            const int prow = mt * 16 + ((lw >> 4) << 2);
#pragma unroll
            for (int j = 0; j < 4; ++j) {
                const int px = prow + j;
                kvs[px][lcol]      = packbf(dk0[j], dv0[j]);
                kvs[px][lcol + 16] = packbf(dk1[j], dv1[j]);
            }
        }
    }

    // ---- MFMA q-pass: 2 B-frags + 2 D live.
    {
        const half8 bq0 = *(const half8*)&wTs[ 0 + lcol][lko];
        const half8 bq1 = *(const half8*)&wTs[16 + lcol][lko];
        const float qeL = qemb[g * CG + lcol];
        const float qeH = qemb[g * CG + lcol + 16];
#pragma unroll 1
        for (int mt = wvid; mt < 9; mt += 4) {
            const half8 a = *(const half8*)&xs16[mt * 16 + lcol][lko];
            const f32x4 dq0 = __builtin_amdgcn_mfma_f32_16x16x32_f16(a, bq0, z4, 0, 0, 0);
            const f32x4 dq1 = __builtin_amdgcn_mfma_f32_16x16x32_f16(a, bq1, z4, 0, 0, 0);
            const int prow = mt * 16 + ((lw >> 4) << 2);
#pragma unroll
            for (int j = 0; j < 4; ++j) {
                const int px = prow + j;
                const int hi2 = px / HT, hj2 = px % HT;
                if (hi2 >= PAD && hi2 < PAD + TILE && hj2 >= PAD && hj2 < PAD + TILE) {
                    const int qp = (hi2 - PAD) * TILE + (hj2 - PAD);
                    qs[qp][lcol]      = (dq0[j] + qeL) * LOG2E;
                    qs[qp][lcol + 16] = (dq1[j] + qeH) * LOG2E;
                }
            }
        }
    }

    // rel row -> 13 packed bf16 pairs (even idx = low half, odd = high half)
    unsigned relp[13];
    {
        const float* rp = rel + (size_t)oc * 25;
#pragma unroll
        for (int i = 0; i < 12; ++i) {
            const unsigned lo = __float_as_uint(rp[2 * i])     + 0x8000u;
            const unsigned hi = __float_as_uint(rp[2 * i + 1]) + 0x8000u;
            relp[i] = (lo >> 16) | (hi & 0xffff0000u);
        }
        relp[12] = (__float_as_uint(rp[24]) + 0x8000u) >> 16;
    }

    __syncthreads();   // MFMA -> phase C

    // q (already *log2e) for this thread's 8 column pixels
    float qreg[8];
#pragma unroll
    for (int ii = 0; ii < 8; ++ii) qreg[ii] = qs[ii * TILE + p0][c];

    // ---- Phase C: monolithic row-streaming attention (champion structure).
    float s_[8], a_[8];
#pragma unroll
    for (int ii = 0; ii < 8; ++ii) { s_[ii] = 0.f; a_[ii] = 0.f; }

#pragma unroll
    for (int h = 0; h < HT; ++h) {
        float kr[5], vr[5];
#pragma unroll
        for (int j = 0; j < 5; ++j) {
            const unsigned u = kvs[h * HT + p0 + j][c];
            kr[j] = __uint_as_float(u << 16);          // bf16 k -> f32
            vr[j] = __uint_as_float(u & 0xffff0000u);  // bf16 v -> f32
        }
#pragma unroll
        for (int ii = 0; ii < 8; ++ii) {
            const int di = h - ii;               // compile-time after unroll
            if (di >= 0 && di < 5) {
                const float qv = qreg[ii];
#pragma unroll
                for (int j = 0; j < 5; ++j) {
                    const int idx = di * 5 + j;  // compile-time
                    const unsigned ru = relp[idx >> 1];
                    const float rl = __uint_as_float((idx & 1) ? (ru & 0xffff0000u)
                                                               : (ru << 16));
                    const float e = __builtin_amdgcn_exp2f(qv * (kr[j] + rl));
                    s_[ii] += e;
                    a_[ii] = fmaf(e, vr[j], a_[ii]);
                }
            }
        }
    }

#pragma unroll
    for (int ii = 0; ii < 8; ++ii) {
        const int gh = ti * TILE + ii, gw = tj * TILE + p0;
        out[(((size_t)b * TH + gh) * TW + gw) * TC + g * CG + c] =
            a_[ii] * __builtin_amdgcn_rcpf(s_[ii]);
    }
}

extern "C" void kernel_launch(void* const* d_in, const int* in_sizes, int n_in,
                              void* d_out, int out_size, void* d_ws, size_t ws_size,
                              hipStream_t stream) {
    const float* x    = (const float*)d_in[0];
    const float* wq   = (const float*)d_in[1];
    const float* wk   = (const float*)d_in[2];
    const float* wv   = (const float*)d_in[3];
    const float* rel  = (const float*)d_in[4];
    const float* qemb = (const float*)d_in[5];
    float* out = (float*)d_out;

    const int nblocks = TB * NT * NT * G;   // 4*7*7*8 = 1568
    hipLaunchKernelGGL(fused_attn_conv_kernel, dim3(nblocks), dim3(256), 0, stream,
                       x, wq, wk, wv, rel, qemb, out);
}

// Round 28
// 38.087 us; speedup vs baseline: 1.3515x; 1.0482x over previous
//
#include <hip/hip_runtime.h>

// AttentionConvFull: grouped 1x1 QKV + 5x5 per-channel local attention, FUSED.
// B=4, H=W=56, C=OC=256, G=8, Cg=32, K=5, pad=2.
//
// R28 = R27 (39.9us) + LDS diet to cross the 4-blocks/CU line (<=40960B):
//  - qs ALIASED onto wTs storage (wTs dead after B-frags hoisted to regs;
//    3 barriers: stage -> B-frag loads -> MFMA -> phase C).
//  - qs stored as bf16 u16 [64][34] (4.25KB, fits wTs's 7.5KB): q*log2e
//    bf16 err ~0.007 abs -> ~0.6% softmax-weight error (threshold has 2.4x).
//  LDS: xs16 11.25K + wTs/qs 7.5K + kvs 18.6K = 38.2KB (was 46.7 -> 3 blk).
// Residual ~8-reg spill (VGPR 128, WRITE ~21MB) ACCEPTED: R24-R27 proved
// demand-136 is distributed (5 targeted diets failed); R26 proved paying
// with the >128 band costs more (51.5us).
//
// MFMA geometry (m89-verified): D[144x96] = A[144x32] x B[32x96];
// A frag: lane(row=lw&15, k=(lw>>4)*8+j); B frag: B[k][col]=wTs[col][k];
// D: col=lane&15, row=(lane>>4)*4+reg. 16x16x32_f16, 54 MFMA/block.
// XP=40 (80B rows) keeps b128 frag reads 16B-aligned.
//
// Precision ledger: f16 proj + bf16 k,v/rel = 2.34e-2 measured (R19-R27);
// + bf16 q adds ~6e-3 worst-case; threshold 5.69e-2.

constexpr int TB = 4, TH = 56, TW = 56, TC = 256;
constexpr int G  = 8, CG = 32, PAD = 2;
constexpr int TILE = 8;
constexpr int HT = TILE + 2 * PAD;   // 12
constexpr int NT = TH / TILE;        // 7
constexpr int NPIX_HALO = HT * HT;   // 144
constexpr int XP = 40;               // padded row (halves) for xs16/wTs
constexpr int KP = 33;               // padded row (words) for kvs
constexpr int QP = 34;               // padded row (u16) for qs alias
constexpr float LOG2E = 1.44269504088896340736f;

typedef __fp16 half2_t __attribute__((ext_vector_type(2)));
typedef __fp16 half8   __attribute__((ext_vector_type(8)));
typedef float  f32x4   __attribute__((ext_vector_type(4)));

__device__ __forceinline__ unsigned h2u(half2_t h) {
    union { half2_t h; unsigned u; } cv; cv.h = h; return cv.u;
}
__device__ __forceinline__ unsigned packbf(float k, float v) {
    return ((__float_as_uint(k) + 0x8000u) >> 16) |
           ((__float_as_uint(v) + 0x8000u) & 0xffff0000u);
}
__device__ __forceinline__ unsigned short packq(float q) {
    return (unsigned short)((__float_as_uint(q) + 0x8000u) >> 16);
}

__global__ __launch_bounds__(256, 2)
void fused_attn_conv_kernel(const float* __restrict__ x,
                            const float* __restrict__ wq,
                            const float* __restrict__ wk,
                            const float* __restrict__ wv,
                            const float* __restrict__ rel,
                            const float* __restrict__ qemb,
                            float* __restrict__ out) {
    __shared__ __align__(16) __fp16 xs16[NPIX_HALO][XP];  // 11.25 KB
    __shared__ __align__(16) __fp16 wTs[3 * CG][XP];      // 7.5 KB (then qs)
    __shared__ unsigned kvs[NPIX_HALO][KP];               // 18.6 KB
    // qs alias: valid only AFTER barrier2 (B-frags already in registers)
    unsigned short (*qs)[QP] = (unsigned short(*)[QP])&wTs[0][0];  // 4.25 KB

    const int bid  = blockIdx.x;
    const int g    = bid & 7;
    const int tile = bid >> 3;
    const int tj   = tile % NT;
    const int ti   = (tile / NT) % NT;
    const int b    = tile / (NT * NT);

    const int t  = threadIdx.x;
    const int c  = t & 31;
    const int p0 = t >> 5;

    const int oc = g * CG + c;           // global out-channel (phase C)
    const int h0 = ti * TILE - PAD, w0 = tj * TILE - PAD;

    // ---- Stage x halo -> xs16 (f16 pairs; 2304 u32, 9/thread, coalesced).
    unsigned (*xsu)[XP / 2] = (unsigned(*)[XP / 2])xs16;
#pragma unroll 3
    for (int r = 0; r < 9; ++r) {
        const int f  = t + r * 256;          // 0..2303
        const int px = f >> 4, pr = f & 15;  // 16 channel-pairs per pixel
        const int hi = px / HT, hj = px % HT;
        const int gh = h0 + hi, gw = w0 + hj;
        unsigned val = 0u;
        if (gh >= 0 && gh < TH && gw >= 0 && gw < TW) {
            const float2 xv = *(const float2*)(x + (((size_t)b * TH + gh) * TW + gw) * TC
                                                 + g * CG + pr * 2);
            val = h2u(__builtin_amdgcn_cvt_pkrtz(xv.x, xv.y));
        }
        xsu[px][pr] = val;
    }

    // ---- Stage weights -> wTs (rows 0-31 wq, 32-63 wk, 64-95 wv).
    {
        unsigned (*wTu)[XP / 2] = (unsigned(*)[XP / 2])wTs;
        const float* wsrc[3] = {wq, wk, wv};
#pragma unroll
        for (int m = 0; m < 3; ++m) {
#pragma unroll
            for (int r = 0; r < 2; ++r) {
                const int f = t + r * 256;           // 0..511 float2 idx
                const int row = f >> 4, pr = f & 15; // row=oc 0..31
                const float2 wv2 = *(const float2*)(wsrc[m] + ((size_t)(g * CG + row)) * CG
                                                            + pr * 2);
                wTu[m * CG + row][pr] = h2u(__builtin_amdgcn_cvt_pkrtz(wv2.x, wv2.y));
            }
        }
    }

    __syncthreads();   // barrier1: stage -> B-frag loads

    const int wvid = t >> 6, lw = t & 63;
    const int lcol = lw & 15;
    const int lko  = (lw >> 4) * 8;
    const f32x4 z4 = {0.f, 0.f, 0.f, 0.f};

    // ---- Hoist ALL 6 B-frags (wTs dead afterwards; qs may alias it).
    const half8 bq0 = *(const half8*)&wTs[ 0 + lcol][lko];
    const half8 bq1 = *(const half8*)&wTs[16 + lcol][lko];
    const half8 bk0 = *(const half8*)&wTs[32 + lcol][lko];
    const half8 bk1 = *(const half8*)&wTs[48 + lcol][lko];
    const half8 bv0 = *(const half8*)&wTs[64 + lcol][lko];
    const half8 bv1 = *(const half8*)&wTs[80 + lcol][lko];
    const float qeL = qemb[g * CG + lcol];
    const float qeH = qemb[g * CG + lcol + 16];

    __syncthreads();   // barrier2: all B-frags loaded -> qs alias is safe

    // ---- MFMA kv-pass: 4 D live.
#pragma unroll 1
    for (int mt = wvid; mt < 9; mt += 4) {        // waves: 3/2/2/2 M-tiles
        const half8 a = *(const half8*)&xs16[mt * 16 + lcol][lko];
        const f32x4 dk0 = __builtin_amdgcn_mfma_f32_16x16x32_f16(a, bk0, z4, 0, 0, 0);
        const f32x4 dk1 = __builtin_amdgcn_mfma_f32_16x16x32_f16(a, bk1, z4, 0, 0, 0);
        const f32x4 dv0 = __builtin_amdgcn_mfma_f32_16x16x32_f16(a, bv0, z4, 0, 0, 0);
        const f32x4 dv1 = __builtin_amdgcn_mfma_f32_16x16x32_f16(a, bv1, z4, 0, 0, 0);
        const int prow = mt * 16 + ((lw >> 4) << 2);
#pragma unroll
        for (int j = 0; j < 4; ++j) {
            const int px = prow + j;
            kvs[px][lcol]      = packbf(dk0[j], dv0[j]);
            kvs[px][lcol + 16] = packbf(dk1[j], dv1[j]);
        }
    }

    // ---- MFMA q-pass: 2 D live; q (bf16, *log2e) -> qs (aliased on wTs).
#pragma unroll 1
    for (int mt = wvid; mt < 9; mt += 4) {
        const half8 a = *(const half8*)&xs16[mt * 16 + lcol][lko];
        const f32x4 dq0 = __builtin_amdgcn_mfma_f32_16x16x32_f16(a, bq0, z4, 0, 0, 0);
        const f32x4 dq1 = __builtin_amdgcn_mfma_f32_16x16x32_f16(a, bq1, z4, 0, 0, 0);
        const int prow = mt * 16 + ((lw >> 4) << 2);
#pragma unroll
        for (int j = 0; j < 4; ++j) {
            const int px = prow + j;
            const int hi2 = px / HT, hj2 = px % HT;
            if (hi2 >= PAD && hi2 < PAD + TILE && hj2 >= PAD && hj2 < PAD + TILE) {
                const int qp = (hi2 - PAD) * TILE + (hj2 - PAD);
                qs[qp][lcol]      = packq((dq0[j] + qeL) * LOG2E);
                qs[qp][lcol + 16] = packq((dq1[j] + qeH) * LOG2E);
            }
        }
    }

    // rel row -> 13 packed bf16 pairs (even idx = low half, odd = high half)
    unsigned relp[13];
    {
        const float* rp = rel + (size_t)oc * 25;
#pragma unroll
        for (int i = 0; i < 12; ++i) {
            const unsigned lo = __float_as_uint(rp[2 * i])     + 0x8000u;
            const unsigned hi = __float_as_uint(rp[2 * i + 1]) + 0x8000u;
            relp[i] = (lo >> 16) | (hi & 0xffff0000u);
        }
        relp[12] = (__float_as_uint(rp[24]) + 0x8000u) >> 16;
    }

    __syncthreads();   // barrier3: MFMA -> phase C

    // q (bf16, already *log2e) for this thread's 8 column pixels
    float qreg[8];
#pragma unroll
    for (int ii = 0; ii < 8; ++ii)
        qreg[ii] = __uint_as_float((unsigned)qs[ii * TILE + p0][c] << 16);

    // ---- Phase C: monolithic row-streaming attention (champion structure).
    float s_[8], a_[8];
#pragma unroll
    for (int ii = 0; ii < 8; ++ii) { s_[ii] = 0.f; a_[ii] = 0.f; }

#pragma unroll
    for (int h = 0; h < HT; ++h) {
        float kr[5], vr[5];
#pragma unroll
        for (int j = 0; j < 5; ++j) {
            const unsigned u = kvs[h * HT + p0 + j][c];
            kr[j] = __uint_as_float(u << 16);          // bf16 k -> f32
            vr[j] = __uint_as_float(u & 0xffff0000u);  // bf16 v -> f32
        }
#pragma unroll
        for (int ii = 0; ii < 8; ++ii) {
            const int di = h - ii;               // compile-time after unroll
            if (di >= 0 && di < 5) {
                const float qv = qreg[ii];
#pragma unroll
                for (int j = 0; j < 5; ++j) {
                    const int idx = di * 5 + j;  // compile-time
                    const unsigned ru = relp[idx >> 1];
                    const float rl = __uint_as_float((idx & 1) ? (ru & 0xffff0000u)
                                                               : (ru << 16));
                    const float e = __builtin_amdgcn_exp2f(qv * (kr[j] + rl));
                    s_[ii] += e;
                    a_[ii] = fmaf(e, vr[j], a_[ii]);
                }
            }
        }
    }

#pragma unroll
    for (int ii = 0; ii < 8; ++ii) {
        const int gh = ti * TILE + ii, gw = tj * TILE + p0;
        out[(((size_t)b * TH + gh) * TW + gw) * TC + g * CG + c] =
            a_[ii] * __builtin_amdgcn_rcpf(s_[ii]);
    }
}

extern "C" void kernel_launch(void* const* d_in, const int* in_sizes, int n_in,
                              void* d_out, int out_size, void* d_ws, size_t ws_size,
                              hipStream_t stream) {
    const float* x    = (const float*)d_in[0];
    const float* wq   = (const float*)d_in[1];
    const float* wk   = (const float*)d_in[2];
    const float* wv   = (const float*)d_in[3];
    const float* rel  = (const float*)d_in[4];
    const float* qemb = (const float*)d_in[5];
    float* out = (float*)d_out;

    const int nblocks = TB * NT * NT * G;   // 4*7*7*8 = 1568
    hipLaunchKernelGGL(fused_attn_conv_kernel, dim3(nblocks), dim3(256), 0, stream,
                       x, wq, wk, wv, rel, qemb, out);
}